// Round 13
// baseline (164.820 us; speedup 1.0000x reference)
//
#include <hip/hip_runtime.h>
#include <cstdint>

// CrossLayerAttention on MI355X (gfx950).  B=4 S=1024 H=2048 NH=16 HD=128.
// R13: = R11 (last passing) + balanced qt pairing ONLY. The R12 permlane asm
//      was the correctness bug (wrong lane-exchange orientation) — reverted
//      to shfl_xor; blocks x and x+256 now carry qt {7-s, s} so every CU's
//      two resident attn blocks total exactly 18 kv-tiles.

typedef unsigned short u16;
typedef __bf16 bf16x8 __attribute__((ext_vector_type(8)));
typedef float  f32x4  __attribute__((ext_vector_type(4)));
typedef float  f32x16 __attribute__((ext_vector_type(16)));
typedef uint32_t u32x4 __attribute__((ext_vector_type(4)));

__device__ __forceinline__ u16 f2bf(float f) {
  uint32_t u = __builtin_bit_cast(uint32_t, f);
  u += 0x7fffu + ((u >> 16) & 1u);   // RNE; inputs finite
  return (u16)(u >> 16);
}
__device__ __forceinline__ uint32_t cvtpk(float lo, float hi) {
  uint32_t r;
  asm("v_cvt_pk_bf16_f32 %0, %1, %2" : "=v"(r) : "v"(lo), "v"(hi));
  return r;
}
__device__ __forceinline__ void gld16(const void* g, void* l) {
  __builtin_amdgcn_global_load_lds(
      (const __attribute__((address_space(1))) void*)g,
      (__attribute__((address_space(3))) void*)l, 16, 0, 0);
}

// ---------------- fp32 -> bf16 convert ----------------
__global__ __launch_bounds__(256) void cvt_kernel(const float* __restrict__ in,
                                                  u16* __restrict__ out, int n4) {
  int i = blockIdx.x * 256 + threadIdx.x;
  if (i < n4) {
    float4 v = ((const float4*)in)[i];
    ushort4 o;
    o.x = f2bf(v.x); o.y = f2bf(v.y); o.z = f2bf(v.z); o.w = f2bf(v.w);
    ((ushort4*)out)[i] = o;
  }
}

// ---------------- per-bh transpose + cvt: out[c][r] = bf16(in[r][c]) ----------------
__global__ __launch_bounds__(256) void transpose_cvt(const float* __restrict__ in,
                                                     u16* __restrict__ out, int R, int C) {
  __shared__ float tile[32][33];
  const int bh = blockIdx.x;
  const int nct = C >> 5;
  const int rt = blockIdx.y / nct, ct = blockIdx.y % nct;
  const float* src = in + (size_t)bh * R * C;
  u16* dst = out + (size_t)bh * R * C;
  const int r = threadIdx.x >> 3, c4 = (threadIdx.x & 7) * 4;
  float4 v = *(const float4*)(src + (size_t)(rt * 32 + r) * C + ct * 32 + c4);
  tile[r][c4 + 0] = v.x; tile[r][c4 + 1] = v.y;
  tile[r][c4 + 2] = v.z; tile[r][c4 + 3] = v.w;
  __syncthreads();
  ushort4 o;
  o.x = f2bf(tile[c4 + 0][r]); o.y = f2bf(tile[c4 + 1][r]);
  o.z = f2bf(tile[c4 + 2][r]); o.w = f2bf(tile[c4 + 3][r]);
  *(ushort4*)(dst + (size_t)(ct * 32 + r) * R + rt * 32 + c4) = o;
}

// ---------------- GEMM: 256x128 tile, BK=64, 3-buf counted-vmcnt pipeline ----------------
// MODE 0: out = A@B^T + bias (fp32 out).  MODE 1: q-proj + fused RoPE (bf16 out,
// scale*log2e folded; head = blockIdx.y; in-wave rope pairing via col interleave).
template<int MODE>
__global__ __launch_bounds__(512, 1)
void gemm256(const u16* __restrict__ A, const u16* __restrict__ Bm,
             const float* __restrict__ bias, const float* __restrict__ cosb,
             const float* __restrict__ sinb, void* __restrict__ Cout) {
  constexpr int K = 2048, N = 2048, NT = 32;
  __shared__ __align__(16) u16 LA[3][256 * 64];   // 3 x 32 KB
  __shared__ __align__(16) u16 LB[3][128 * 64];   // 3 x 16 KB
  const int t = threadIdx.x, lane = t & 63, w = t >> 6;
  const int row0 = blockIdx.x * 256, col0 = blockIdx.y * 128;
  const int wr = (w >> 1) * 64;
  const int g = w & 1;
  const int fr = lane & 15, fg = lane >> 4, fx = fr & 7;
  const int sb8 = ((t & 7) ^ ((t >> 3) & 7)) * 8;
  const u16* gA = A  + (size_t)(row0 + (t >> 3)) * K + sb8;
  const u16* gB = Bm + (size_t)(col0 + (t >> 3)) * K + sb8;
  const int lo8 = t * 8;

  int brow[4];
  if constexpr (MODE == 1) {
    brow[0] = g * 32 + fr;      brow[1] = g * 32 + 16 + fr;
    brow[2] = g * 32 + 64 + fr; brow[3] = g * 32 + 80 + fr;
  } else {
    brow[0] = g * 64 + fr;      brow[1] = g * 64 + 16 + fr;
    brow[2] = g * 64 + 32 + fr; brow[3] = g * 64 + 48 + fr;
  }

  f32x4 acc[4][4] = {};

  auto SA0 = [&](int kt, int buf) {
    const int k0 = kt * 64;
    gld16(gA + k0,                    &LA[buf][lo8]);
    gld16(gA + k0 + (size_t)64 * K,   &LA[buf][4096 + lo8]);
    gld16(gB + k0,                    &LB[buf][lo8]);
  };
  auto SA1 = [&](int kt, int buf) {
    const int k0 = kt * 64;
    gld16(gA + k0 + (size_t)128 * K,  &LA[buf][8192 + lo8]);
    gld16(gA + k0 + (size_t)192 * K,  &LA[buf][12288 + lo8]);
    gld16(gB + k0 + (size_t)64 * K,   &LB[buf][4096 + lo8]);
  };

  SA0(0, 0); SA1(0, 0);
  SA0(1, 1); SA1(1, 1);

  int cb = 0;
  for (int kt = 0; kt < NT; ++kt) {
    const int sbuf = cb >= 1 ? cb - 1 : cb + 2;
    if (kt < NT - 1) asm volatile("s_waitcnt vmcnt(6)" ::: "memory");
    else             asm volatile("s_waitcnt vmcnt(0)" ::: "memory");
    __builtin_amdgcn_s_barrier();
    asm volatile("" ::: "memory");

    bf16x8 af[4][2], bq0[2][2];
#pragma unroll
    for (int mi = 0; mi < 4; mi++)
#pragma unroll
      for (int ks = 0; ks < 2; ks++)
        af[mi][ks] = *(const bf16x8*)&LA[cb][(wr + mi * 16 + fr) * 64 + ((ks * 4 + fg) ^ fx) * 8];
#pragma unroll
    for (int ni = 0; ni < 2; ni++)
#pragma unroll
      for (int ks = 0; ks < 2; ks++)
        bq0[ni][ks] = *(const bf16x8*)&LB[cb][brow[ni] * 64 + ((ks * 4 + fg) ^ fx) * 8];
    if (kt + 2 < NT) SA0(kt + 2, sbuf);
    __builtin_amdgcn_s_setprio(1);
#pragma unroll
    for (int ks = 0; ks < 2; ks++)
#pragma unroll
      for (int mi = 0; mi < 4; mi++)
#pragma unroll
        for (int ni = 0; ni < 2; ni++)
          acc[mi][ni] = __builtin_amdgcn_mfma_f32_16x16x32_bf16(af[mi][ks], bq0[ni][ks], acc[mi][ni], 0, 0, 0);
    __builtin_amdgcn_s_setprio(0);
    __builtin_amdgcn_s_barrier();
    asm volatile("" ::: "memory");

    bf16x8 bq1[2][2];
#pragma unroll
    for (int ni = 0; ni < 2; ni++)
#pragma unroll
      for (int ks = 0; ks < 2; ks++)
        bq1[ni][ks] = *(const bf16x8*)&LB[cb][brow[ni + 2] * 64 + ((ks * 4 + fg) ^ fx) * 8];
    if (kt + 2 < NT) SA1(kt + 2, sbuf);
    __builtin_amdgcn_s_setprio(1);
#pragma unroll
    for (int ks = 0; ks < 2; ks++)
#pragma unroll
      for (int mi = 0; mi < 4; mi++)
#pragma unroll
        for (int ni = 0; ni < 2; ni++)
          acc[mi][ni + 2] = __builtin_amdgcn_mfma_f32_16x16x32_bf16(af[mi][ks], bq1[ni][ks], acc[mi][ni + 2], 0, 0, 0);
    __builtin_amdgcn_s_setprio(0);

    cb = cb == 2 ? 0 : cb + 1;
  }

  if constexpr (MODE == 0) {
#pragma unroll
    for (int mi = 0; mi < 4; mi++)
#pragma unroll
      for (int ni = 0; ni < 4; ni++) {
        int col = col0 + brow[ni];
        float bv = bias[col];
#pragma unroll
        for (int i = 0; i < 4; i++) {
          int row = row0 + wr + mi * 16 + fg * 4 + i;
          ((float*)Cout)[(size_t)row * N + col] = acc[mi][ni][i] + bv;
        }
      }
  } else {
    const int h = blockIdx.y;
    const float SL2E = 0.12751743f;               // (1/sqrt(128)) * log2(e)
    float bv[4];
#pragma unroll
    for (int ni = 0; ni < 4; ni++) bv[ni] = bias[h * 128 + brow[ni]];
    u16* qout = (u16*)Cout;
#pragma unroll
    for (int mi = 0; mi < 4; mi++)
#pragma unroll
      for (int i = 0; i < 4; i++) {
        int row = row0 + wr + mi * 16 + fg * 4 + i;
        int s = row & 1023, bb = row >> 10;
        size_t obase = (((size_t)(bb * 16 + h)) * 1024 + s) * 128;
#pragma unroll
        for (int dp = 0; dp < 2; dp++) {
          int d = g * 32 + dp * 16 + fr;
          float c  = cosb[s * 128 + d] * SL2E;
          float sn = sinb[s * 128 + d] * SL2E;
          float qlo = acc[mi][dp][i] + bv[dp];
          float qhi = acc[mi][dp + 2][i] + bv[dp + 2];
          qout[obase + d]      = f2bf(qlo * c - qhi * sn);
          qout[obase + d + 64] = f2bf(qhi * c + qlo * sn);
        }
      }
  }
}

// ---------------- Flash attention: balanced pairs (R11 math, verified) ----------------
// 512 blocks x 256 thr (4 waves, BQ=128, KVBLK=64, dbuf). slice = x>>6:
// qt = slice<4 ? 7-slice : slice-4 -> blocks x and x+256 (same CU under
// linear dispatch) carry qt {7-s, s}: every CU totals 18 kv-tiles. bh = x&63.
__global__ __launch_bounds__(256, 1)
void attn_kernel(const u16* __restrict__ qbf, const u16* __restrict__ kTb,
                 const u16* __restrict__ vTb, u16* __restrict__ aout) {
  __shared__ __align__(16) u16 Kb[2][64 * 128];   // 2 x 16 KB
  __shared__ __align__(16) u16 Vb[2][128 * 64];   // 2 x 16 KB
  const int t = threadIdx.x, lane = t & 63, w = t >> 6;   // w in 0..3
  const int x = blockIdx.x;
  const int slice = x >> 6;
  const int qt = slice < 4 ? 7 - slice : slice - 4;
  const int bh = x & 63;
  const int b = bh >> 4, h = bh & 15;
  const int q31 = lane & 31, hi = lane >> 5, kx7 = q31 & 7;
  const u16* kbase = kTb + (size_t)bh * 131072;   // [s][d]
  const u16* vbase = vTb + (size_t)bh * 131072;   // [d][s]

  const int kRow = t >> 4;
  const int kCb  = (t & 15) ^ (kRow & 7);
  const int vRow = t >> 3;
  const int vCb  = (t & 7) ^ (vRow & 7);

  const int rw0 = qt * 128 + w * 32;
  const int rowg = rw0 + q31;
  const int last = 2 * qt + 1;
  const int wlast = 2 * qt + (w >> 1);

  bf16x8 qf[8];
#pragma unroll
  for (int ds = 0; ds < 8; ds++)
    qf[ds] = *(const bf16x8*)&qbf[((size_t)bh * 1024 + rowg) * 128 + ds * 16 + hi * 8];

  f32x16 acc[4] = {};
  float m = -3e38f, l = 0.f;

  auto STAGE = [&](int kt, int buf) {
    const u16* ks = kbase + (size_t)(kt * 64 + kRow) * 128 + kCb * 8;
    const u16* vs = vbase + (size_t)vRow * 1024 + kt * 64 + vCb * 8;
    u16* kl = &Kb[buf][t * 8];
    u16* vl = &Vb[buf][t * 8];
#pragma unroll
    for (int p = 0; p < 4; p++) {
      gld16(ks + (size_t)p * 16 * 128, kl + p * 2048);
      gld16(vs + (size_t)p * 32 * 1024, vl + p * 2048);
    }
  };

  STAGE(0, 0);
  __syncthreads();
  for (int kt = 0; kt <= last; kt++) {
    const int cur = kt & 1;
    if (kt < last) STAGE(kt + 1, cur ^ 1);
    if (kt <= wlast) {
      // ---- QK^T (swapped), log2 domain ----
      f32x16 sa0 = {}, sa1 = {};
      __builtin_amdgcn_s_setprio(1);
#pragma unroll
      for (int ds = 0; ds < 8; ds++) {
        bf16x8 k0 = *(const bf16x8*)&Kb[cur][q31 * 128 + (((2 * ds + hi) ^ kx7) * 8)];
        bf16x8 k1 = *(const bf16x8*)&Kb[cur][(q31 + 32) * 128 + (((2 * ds + hi) ^ kx7) * 8)];
        sa0 = __builtin_amdgcn_mfma_f32_32x32x16_bf16(k0, qf[ds], sa0, 0, 0, 0);
        sa1 = __builtin_amdgcn_mfma_f32_32x32x16_bf16(k1, qf[ds], sa1, 0, 0, 0);
      }
      __builtin_amdgcn_s_setprio(0);

      if (kt == wlast) {
#pragma unroll
        for (int rr = 0; rr < 16; rr++) {
          int cr = (rr & 3) + 8 * (rr >> 2) + 4 * hi;
          if (kt * 64 + cr > rowg)      sa0[rr] = -1e9f;
          if (kt * 64 + 32 + cr > rowg) sa1[rr] = -1e9f;
        }
      }
      float t0 = fmaxf(fmaxf(sa0[0], sa0[1]), sa0[2]);
      float t1 = fmaxf(fmaxf(sa0[3], sa0[4]), sa0[5]);
      float t2 = fmaxf(fmaxf(sa0[6], sa0[7]), sa0[8]);
      float t3 = fmaxf(fmaxf(sa0[9], sa0[10]), sa0[11]);
      float t4 = fmaxf(fmaxf(sa0[12], sa0[13]), sa0[14]);
      float u0 = fmaxf(fmaxf(sa1[0], sa1[1]), sa1[2]);
      float u1 = fmaxf(fmaxf(sa1[3], sa1[4]), sa1[5]);
      float u2 = fmaxf(fmaxf(sa1[6], sa1[7]), sa1[8]);
      float u3 = fmaxf(fmaxf(sa1[9], sa1[10]), sa1[11]);
      float u4 = fmaxf(fmaxf(sa1[12], sa1[13]), sa1[14]);
      float mx = fmaxf(fmaxf(fmaxf(fmaxf(t0, t1), fmaxf(t2, t3)),
                             fmaxf(fmaxf(t4, sa0[15]), fmaxf(u0, u1))),
                       fmaxf(fmaxf(u2, u3), fmaxf(u4, sa1[15])));
      mx = fmaxf(mx, __shfl_xor(mx, 32));
      if (!__all(mx - m <= 11.5f)) {              // defer-max (T13, log2 units)
        float mn = fmaxf(m, mx);
        float corr = __builtin_amdgcn_exp2f(m - mn);
        m = mn; l *= corr;
#pragma unroll
        for (int nd = 0; nd < 4; nd++)
#pragma unroll
          for (int rr = 0; rr < 16; rr++) acc[nd][rr] *= corr;
      }
#pragma unroll
      for (int rr = 0; rr < 16; rr++) {
        sa0[rr] = __builtin_amdgcn_exp2f(sa0[rr] - m);
        sa1[rr] = __builtin_amdgcn_exp2f(sa1[rr] - m);
      }
      {
        float s0 = (sa0[0] + sa0[1]) + (sa0[2] + sa0[3]);
        float s1 = (sa0[4] + sa0[5]) + (sa0[6] + sa0[7]);
        float s2 = (sa0[8] + sa0[9]) + (sa0[10] + sa0[11]);
        float s3 = (sa0[12] + sa0[13]) + (sa0[14] + sa0[15]);
        float s4 = (sa1[0] + sa1[1]) + (sa1[2] + sa1[3]);
        float s5 = (sa1[4] + sa1[5]) + (sa1[6] + sa1[7]);
        float s6 = (sa1[8] + sa1[9]) + (sa1[10] + sa1[11]);
        float s7 = (sa1[12] + sa1[13]) + (sa1[14] + sa1[15]);
        float sum = ((s0 + s1) + (s2 + s3)) + ((s4 + s5) + (s6 + s7));
        sum += __shfl_xor(sum, 32);
        l += sum;
      }

      // ---- P -> bf16 A-frags via v_cvt_pk + shfl_xor(32) (T12) + PV ----
      __builtin_amdgcn_s_setprio(1);
      uint32_t wA = cvtpk(sa0[0], sa0[1]),   wB = cvtpk(sa0[2], sa0[3]);
      uint32_t wC = cvtpk(sa0[4], sa0[5]),   wD = cvtpk(sa0[6], sa0[7]);
      uint32_t wE = cvtpk(sa0[8], sa0[9]),   wF = cvtpk(sa0[10], sa0[11]);
      uint32_t wG = cvtpk(sa0[12], sa0[13]), wH = cvtpk(sa0[14], sa0[15]);
      uint32_t wI = cvtpk(sa1[0], sa1[1]),   wJ = cvtpk(sa1[2], sa1[3]);
      uint32_t wK = cvtpk(sa1[4], sa1[5]),   wL = cvtpk(sa1[6], sa1[7]);
      uint32_t wM = cvtpk(sa1[8], sa1[9]),   wN = cvtpk(sa1[10], sa1[11]);
      uint32_t wO = cvtpk(sa1[12], sa1[13]), wP = cvtpk(sa1[14], sa1[15]);
      uint32_t xA = __shfl_xor(wA, 32), xB = __shfl_xor(wB, 32);
      uint32_t xC = __shfl_xor(wC, 32), xD = __shfl_xor(wD, 32);
      uint32_t xE = __shfl_xor(wE, 32), xF = __shfl_xor(wF, 32);
      uint32_t xG = __shfl_xor(wG, 32), xH = __shfl_xor(wH, 32);
      uint32_t xI = __shfl_xor(wI, 32), xJ = __shfl_xor(wJ, 32);
      uint32_t xK = __shfl_xor(wK, 32), xL = __shfl_xor(wL, 32);
      uint32_t xM = __shfl_xor(wM, 32), xN = __shfl_xor(wN, 32);
      uint32_t xO = __shfl_xor(wO, 32), xP = __shfl_xor(wP, 32);
#pragma unroll
      for (int ks = 0; ks < 4; ks++) {
        u32x4 aw;
        if (ks == 0) {
          aw.x = hi ? xC : wA;  aw.y = hi ? xD : wB;
          aw.z = hi ? wC : xA;  aw.w = hi ? wD : xB;
        } else if (ks == 1) {
          aw.x = hi ? xG : wE;  aw.y = hi ? xH : wF;
          aw.z = hi ? wG : xE;  aw.w = hi ? wH : xF;
        } else if (ks == 2) {
          aw.x = hi ? xK : wI;  aw.y = hi ? xL : wJ;
          aw.z = hi ? wK : xI;  aw.w = hi ? wL : xJ;
        } else {
          aw.x = hi ? xO : wM;  aw.y = hi ? xP : wN;
          aw.z = hi ? wO : xM;  aw.w = hi ? wP : xN;
        }
        bf16x8 af = __builtin_bit_cast(bf16x8, aw);
#pragma unroll
        for (int nd = 0; nd < 4; nd++) {
          bf16x8 vf = *(const bf16x8*)&Vb[cur][(nd * 32 + q31) * 64 + (((2 * ks + hi) ^ kx7) * 8)];
          acc[nd] = __builtin_amdgcn_mfma_f32_32x32x16_bf16(af, vf, acc[nd], 0, 0, 0);
        }
      }
      __builtin_amdgcn_s_setprio(0);
    }
    __syncthreads();
  }

  // ---- epilogue ----
  float linv = 1.f / l;
#pragma unroll
  for (int rr = 0; rr < 16; rr++) {
    int cr = (rr & 3) + 8 * (rr >> 2) + 4 * hi;
    float li = __shfl(linv, cr);
    int sg = rw0 + cr;
    size_t obase = (((size_t)b * 1024 + sg) * 16 + h) * 128 + q31;
#pragma unroll
    for (int nd = 0; nd < 4; nd++)
      aout[obase + nd * 32] = f2bf(acc[nd][rr] * li);
  }
}

// ---------------- launcher ----------------
extern "C" void kernel_launch(void* const* d_in, const int* in_sizes, int n_in,
                              void* d_out, int out_size, void* d_ws, size_t ws_size,
                              hipStream_t stream) {
  const float* hs  = (const float*)d_in[0];
  const float* key = (const float*)d_in[1];
  const float* val = (const float*)d_in[2];
  // d_in[3]: attention_mask — causal, reproduced analytically
  const float* rc  = (const float*)d_in[4];
  const float* rs  = (const float*)d_in[5];
  const float* wq  = (const float*)d_in[6];
  const float* bq  = (const float*)d_in[7];
  const float* wo  = (const float*)d_in[8];
  const float* bo  = (const float*)d_in[9];
  float* out = (float*)d_out;

  char* ws = (char*)d_ws;
  u16* hs_bf = (u16*)(ws);                   // 16 MB ; reused as attn_bf
  u16* wq_bf = (u16*)(ws + 16777216);        //  8 MB
  u16* wo_bf = (u16*)(ws + 25165824);        //  8 MB
  u16* q_bf  = (u16*)(ws + 33554432);        // 16 MB
  u16* kT    = (u16*)(ws + 50331648);        // 16 MB  [bh][s][d]
  u16* vT    = (u16*)(ws + 67108864);        // 16 MB  [bh][d][s]
  u16* attn_bf = hs_bf;                      // hs_bf dead after gemm_rope

  cvt_kernel<<<8192, 256, 0, stream>>>(hs, hs_bf, 8388608 / 4);
  cvt_kernel<<<4096, 256, 0, stream>>>(wq, wq_bf, 4194304 / 4);
  cvt_kernel<<<4096, 256, 0, stream>>>(wo, wo_bf, 4194304 / 4);

  transpose_cvt<<<dim3(64, 128), 256, 0, stream>>>(key, kT, 128, 1024);   // -> kT[bh][s][d]
  transpose_cvt<<<dim3(64, 128), 256, 0, stream>>>(val, vT, 1024, 128);   // -> vT[bh][d][s]

  gemm256<1><<<dim3(16, 16), 512, 0, stream>>>(hs_bf, wq_bf, bq, rc, rs, q_bf);
  attn_kernel<<<512, 256, 0, stream>>>(q_bf, kT, vT, attn_bf);
  gemm256<0><<<dim3(16, 16), 512, 0, stream>>>(attn_bf, wo_bf, bo, nullptr, nullptr, out);
}

// Round 14
// 153.989 us; speedup vs baseline: 1.0703x; 1.0703x over previous
//
#include <hip/hip_runtime.h>
#include <cstdint>

// CrossLayerAttention on MI355X (gfx950).  B=4 S=1024 H=2048 NH=16 HD=128.
// R14: = R11 (best passing, 160.6us) with the three cvt launches merged into
//      one batched kernel. Attn grid mapping reverted to R11's qt=7-(x>>6)
//      (R13's "balanced" remap measured -6us: co-residency model was wrong).

typedef unsigned short u16;
typedef __bf16 bf16x8 __attribute__((ext_vector_type(8)));
typedef float  f32x4  __attribute__((ext_vector_type(4)));
typedef float  f32x16 __attribute__((ext_vector_type(16)));
typedef uint32_t u32x4 __attribute__((ext_vector_type(4)));

__device__ __forceinline__ u16 f2bf(float f) {
  uint32_t u = __builtin_bit_cast(uint32_t, f);
  u += 0x7fffu + ((u >> 16) & 1u);   // RNE; inputs finite
  return (u16)(u >> 16);
}
__device__ __forceinline__ uint32_t cvtpk(float lo, float hi) {
  uint32_t r;
  asm("v_cvt_pk_bf16_f32 %0, %1, %2" : "=v"(r) : "v"(lo), "v"(hi));
  return r;
}
__device__ __forceinline__ void gld16(const void* g, void* l) {
  __builtin_amdgcn_global_load_lds(
      (const __attribute__((address_space(1))) void*)g,
      (__attribute__((address_space(3))) void*)l, 16, 0, 0);
}

// ---------------- batched fp32 -> bf16 convert (hs | wq | wo in one grid) ----------------
__global__ __launch_bounds__(256) void cvt_all(const float* __restrict__ hs,
                                               const float* __restrict__ wq,
                                               const float* __restrict__ wo,
                                               u16* __restrict__ hs_o,
                                               u16* __restrict__ wq_o,
                                               u16* __restrict__ wo_o) {
  int i = blockIdx.x * 256 + threadIdx.x;        // i in [0, 4194304)
  const float* in;
  u16* out;
  int j;
  if (i < 2097152)      { in = hs; out = hs_o; j = i; }
  else if (i < 3145728) { in = wq; out = wq_o; j = i - 2097152; }
  else                  { in = wo; out = wo_o; j = i - 3145728; }
  float4 v = ((const float4*)in)[j];
  ushort4 o;
  o.x = f2bf(v.x); o.y = f2bf(v.y); o.z = f2bf(v.z); o.w = f2bf(v.w);
  ((ushort4*)out)[j] = o;
}

// ---------------- per-bh transpose + cvt: out[c][r] = bf16(in[r][c]) ----------------
__global__ __launch_bounds__(256) void transpose_cvt(const float* __restrict__ in,
                                                     u16* __restrict__ out, int R, int C) {
  __shared__ float tile[32][33];
  const int bh = blockIdx.x;
  const int nct = C >> 5;
  const int rt = blockIdx.y / nct, ct = blockIdx.y % nct;
  const float* src = in + (size_t)bh * R * C;
  u16* dst = out + (size_t)bh * R * C;
  const int r = threadIdx.x >> 3, c4 = (threadIdx.x & 7) * 4;
  float4 v = *(const float4*)(src + (size_t)(rt * 32 + r) * C + ct * 32 + c4);
  tile[r][c4 + 0] = v.x; tile[r][c4 + 1] = v.y;
  tile[r][c4 + 2] = v.z; tile[r][c4 + 3] = v.w;
  __syncthreads();
  ushort4 o;
  o.x = f2bf(tile[c4 + 0][r]); o.y = f2bf(tile[c4 + 1][r]);
  o.z = f2bf(tile[c4 + 2][r]); o.w = f2bf(tile[c4 + 3][r]);
  *(ushort4*)(dst + (size_t)(ct * 32 + r) * R + rt * 32 + c4) = o;
}

// ---------------- GEMM: 256x128 tile, BK=64, 3-buf counted-vmcnt pipeline ----------------
// MODE 0: out = A@B^T + bias (fp32 out).  MODE 1: q-proj + fused RoPE (bf16 out,
// scale*log2e folded; head = blockIdx.y; in-wave rope pairing via col interleave).
template<int MODE>
__global__ __launch_bounds__(512, 1)
void gemm256(const u16* __restrict__ A, const u16* __restrict__ Bm,
             const float* __restrict__ bias, const float* __restrict__ cosb,
             const float* __restrict__ sinb, void* __restrict__ Cout) {
  constexpr int K = 2048, N = 2048, NT = 32;
  __shared__ __align__(16) u16 LA[3][256 * 64];   // 3 x 32 KB
  __shared__ __align__(16) u16 LB[3][128 * 64];   // 3 x 16 KB
  const int t = threadIdx.x, lane = t & 63, w = t >> 6;
  const int row0 = blockIdx.x * 256, col0 = blockIdx.y * 128;
  const int wr = (w >> 1) * 64;
  const int g = w & 1;
  const int fr = lane & 15, fg = lane >> 4, fx = fr & 7;
  const int sb8 = ((t & 7) ^ ((t >> 3) & 7)) * 8;
  const u16* gA = A  + (size_t)(row0 + (t >> 3)) * K + sb8;
  const u16* gB = Bm + (size_t)(col0 + (t >> 3)) * K + sb8;
  const int lo8 = t * 8;

  int brow[4];
  if constexpr (MODE == 1) {
    brow[0] = g * 32 + fr;      brow[1] = g * 32 + 16 + fr;
    brow[2] = g * 32 + 64 + fr; brow[3] = g * 32 + 80 + fr;
  } else {
    brow[0] = g * 64 + fr;      brow[1] = g * 64 + 16 + fr;
    brow[2] = g * 64 + 32 + fr; brow[3] = g * 64 + 48 + fr;
  }

  f32x4 acc[4][4] = {};

  auto SA0 = [&](int kt, int buf) {
    const int k0 = kt * 64;
    gld16(gA + k0,                    &LA[buf][lo8]);
    gld16(gA + k0 + (size_t)64 * K,   &LA[buf][4096 + lo8]);
    gld16(gB + k0,                    &LB[buf][lo8]);
  };
  auto SA1 = [&](int kt, int buf) {
    const int k0 = kt * 64;
    gld16(gA + k0 + (size_t)128 * K,  &LA[buf][8192 + lo8]);
    gld16(gA + k0 + (size_t)192 * K,  &LA[buf][12288 + lo8]);
    gld16(gB + k0 + (size_t)64 * K,   &LB[buf][4096 + lo8]);
  };

  SA0(0, 0); SA1(0, 0);
  SA0(1, 1); SA1(1, 1);

  int cb = 0;
  for (int kt = 0; kt < NT; ++kt) {
    const int sbuf = cb >= 1 ? cb - 1 : cb + 2;
    if (kt < NT - 1) asm volatile("s_waitcnt vmcnt(6)" ::: "memory");
    else             asm volatile("s_waitcnt vmcnt(0)" ::: "memory");
    __builtin_amdgcn_s_barrier();
    asm volatile("" ::: "memory");

    bf16x8 af[4][2], bq0[2][2];
#pragma unroll
    for (int mi = 0; mi < 4; mi++)
#pragma unroll
      for (int ks = 0; ks < 2; ks++)
        af[mi][ks] = *(const bf16x8*)&LA[cb][(wr + mi * 16 + fr) * 64 + ((ks * 4 + fg) ^ fx) * 8];
#pragma unroll
    for (int ni = 0; ni < 2; ni++)
#pragma unroll
      for (int ks = 0; ks < 2; ks++)
        bq0[ni][ks] = *(const bf16x8*)&LB[cb][brow[ni] * 64 + ((ks * 4 + fg) ^ fx) * 8];
    if (kt + 2 < NT) SA0(kt + 2, sbuf);
    __builtin_amdgcn_s_setprio(1);
#pragma unroll
    for (int ks = 0; ks < 2; ks++)
#pragma unroll
      for (int mi = 0; mi < 4; mi++)
#pragma unroll
        for (int ni = 0; ni < 2; ni++)
          acc[mi][ni] = __builtin_amdgcn_mfma_f32_16x16x32_bf16(af[mi][ks], bq0[ni][ks], acc[mi][ni], 0, 0, 0);
    __builtin_amdgcn_s_setprio(0);
    __builtin_amdgcn_s_barrier();
    asm volatile("" ::: "memory");

    bf16x8 bq1[2][2];
#pragma unroll
    for (int ni = 0; ni < 2; ni++)
#pragma unroll
      for (int ks = 0; ks < 2; ks++)
        bq1[ni][ks] = *(const bf16x8*)&LB[cb][brow[ni + 2] * 64 + ((ks * 4 + fg) ^ fx) * 8];
    if (kt + 2 < NT) SA1(kt + 2, sbuf);
    __builtin_amdgcn_s_setprio(1);
#pragma unroll
    for (int ks = 0; ks < 2; ks++)
#pragma unroll
      for (int mi = 0; mi < 4; mi++)
#pragma unroll
        for (int ni = 0; ni < 2; ni++)
          acc[mi][ni + 2] = __builtin_amdgcn_mfma_f32_16x16x32_bf16(af[mi][ks], bq1[ni][ks], acc[mi][ni + 2], 0, 0, 0);
    __builtin_amdgcn_s_setprio(0);

    cb = cb == 2 ? 0 : cb + 1;
  }

  if constexpr (MODE == 0) {
#pragma unroll
    for (int mi = 0; mi < 4; mi++)
#pragma unroll
      for (int ni = 0; ni < 4; ni++) {
        int col = col0 + brow[ni];
        float bv = bias[col];
#pragma unroll
        for (int i = 0; i < 4; i++) {
          int row = row0 + wr + mi * 16 + fg * 4 + i;
          ((float*)Cout)[(size_t)row * N + col] = acc[mi][ni][i] + bv;
        }
      }
  } else {
    const int h = blockIdx.y;
    const float SL2E = 0.12751743f;               // (1/sqrt(128)) * log2(e)
    float bv[4];
#pragma unroll
    for (int ni = 0; ni < 4; ni++) bv[ni] = bias[h * 128 + brow[ni]];
    u16* qout = (u16*)Cout;
#pragma unroll
    for (int mi = 0; mi < 4; mi++)
#pragma unroll
      for (int i = 0; i < 4; i++) {
        int row = row0 + wr + mi * 16 + fg * 4 + i;
        int s = row & 1023, bb = row >> 10;
        size_t obase = (((size_t)(bb * 16 + h)) * 1024 + s) * 128;
#pragma unroll
        for (int dp = 0; dp < 2; dp++) {
          int d = g * 32 + dp * 16 + fr;
          float c  = cosb[s * 128 + d] * SL2E;
          float sn = sinb[s * 128 + d] * SL2E;
          float qlo = acc[mi][dp][i] + bv[dp];
          float qhi = acc[mi][dp + 2][i] + bv[dp + 2];
          qout[obase + d]      = f2bf(qlo * c - qhi * sn);
          qout[obase + d + 64] = f2bf(qhi * c + qlo * sn);
        }
      }
  }
}

// ---------------- Flash attention (R11 exact): 4 waves, BQ=128, KVBLK=64, dbuf ----------------
// 512 blocks x 256 thr. qt = 7-(x>>6) (longest-first), bh = x&63.
__global__ __launch_bounds__(256, 1)
void attn_kernel(const u16* __restrict__ qbf, const u16* __restrict__ kTb,
                 const u16* __restrict__ vTb, u16* __restrict__ aout) {
  __shared__ __align__(16) u16 Kb[2][64 * 128];   // 2 x 16 KB
  __shared__ __align__(16) u16 Vb[2][128 * 64];   // 2 x 16 KB
  const int t = threadIdx.x, lane = t & 63, w = t >> 6;   // w in 0..3
  const int x = blockIdx.x;
  const int qt = 7 - (x >> 6);
  const int bh = x & 63;
  const int b = bh >> 4, h = bh & 15;
  const int q31 = lane & 31, hi = lane >> 5, kx7 = q31 & 7;
  const u16* kbase = kTb + (size_t)bh * 131072;   // [s][d]
  const u16* vbase = vTb + (size_t)bh * 131072;   // [d][s]

  const int kRow = t >> 4;
  const int kCb  = (t & 15) ^ (kRow & 7);
  const int vRow = t >> 3;
  const int vCb  = (t & 7) ^ (vRow & 7);

  const int rw0 = qt * 128 + w * 32;
  const int rowg = rw0 + q31;
  const int last = 2 * qt + 1;
  const int wlast = 2 * qt + (w >> 1);

  bf16x8 qf[8];
#pragma unroll
  for (int ds = 0; ds < 8; ds++)
    qf[ds] = *(const bf16x8*)&qbf[((size_t)bh * 1024 + rowg) * 128 + ds * 16 + hi * 8];

  f32x16 acc[4] = {};
  float m = -3e38f, l = 0.f;

  auto STAGE = [&](int kt, int buf) {
    const u16* ks = kbase + (size_t)(kt * 64 + kRow) * 128 + kCb * 8;
    const u16* vs = vbase + (size_t)vRow * 1024 + kt * 64 + vCb * 8;
    u16* kl = &Kb[buf][t * 8];
    u16* vl = &Vb[buf][t * 8];
#pragma unroll
    for (int p = 0; p < 4; p++) {
      gld16(ks + (size_t)p * 16 * 128, kl + p * 2048);
      gld16(vs + (size_t)p * 32 * 1024, vl + p * 2048);
    }
  };

  STAGE(0, 0);
  __syncthreads();
  for (int kt = 0; kt <= last; kt++) {
    const int cur = kt & 1;
    if (kt < last) STAGE(kt + 1, cur ^ 1);
    if (kt <= wlast) {
      // ---- QK^T (swapped), log2 domain ----
      f32x16 sa0 = {}, sa1 = {};
      __builtin_amdgcn_s_setprio(1);
#pragma unroll
      for (int ds = 0; ds < 8; ds++) {
        bf16x8 k0 = *(const bf16x8*)&Kb[cur][q31 * 128 + (((2 * ds + hi) ^ kx7) * 8)];
        bf16x8 k1 = *(const bf16x8*)&Kb[cur][(q31 + 32) * 128 + (((2 * ds + hi) ^ kx7) * 8)];
        sa0 = __builtin_amdgcn_mfma_f32_32x32x16_bf16(k0, qf[ds], sa0, 0, 0, 0);
        sa1 = __builtin_amdgcn_mfma_f32_32x32x16_bf16(k1, qf[ds], sa1, 0, 0, 0);
      }
      __builtin_amdgcn_s_setprio(0);

      if (kt == wlast) {
#pragma unroll
        for (int rr = 0; rr < 16; rr++) {
          int cr = (rr & 3) + 8 * (rr >> 2) + 4 * hi;
          if (kt * 64 + cr > rowg)      sa0[rr] = -1e9f;
          if (kt * 64 + 32 + cr > rowg) sa1[rr] = -1e9f;
        }
      }
      float t0 = fmaxf(fmaxf(sa0[0], sa0[1]), sa0[2]);
      float t1 = fmaxf(fmaxf(sa0[3], sa0[4]), sa0[5]);
      float t2 = fmaxf(fmaxf(sa0[6], sa0[7]), sa0[8]);
      float t3 = fmaxf(fmaxf(sa0[9], sa0[10]), sa0[11]);
      float t4 = fmaxf(fmaxf(sa0[12], sa0[13]), sa0[14]);
      float u0 = fmaxf(fmaxf(sa1[0], sa1[1]), sa1[2]);
      float u1 = fmaxf(fmaxf(sa1[3], sa1[4]), sa1[5]);
      float u2 = fmaxf(fmaxf(sa1[6], sa1[7]), sa1[8]);
      float u3 = fmaxf(fmaxf(sa1[9], sa1[10]), sa1[11]);
      float u4 = fmaxf(fmaxf(sa1[12], sa1[13]), sa1[14]);
      float mx = fmaxf(fmaxf(fmaxf(fmaxf(t0, t1), fmaxf(t2, t3)),
                             fmaxf(fmaxf(t4, sa0[15]), fmaxf(u0, u1))),
                       fmaxf(fmaxf(u2, u3), fmaxf(u4, sa1[15])));
      mx = fmaxf(mx, __shfl_xor(mx, 32));
      if (!__all(mx - m <= 11.5f)) {              // defer-max (T13, log2 units)
        float mn = fmaxf(m, mx);
        float corr = __builtin_amdgcn_exp2f(m - mn);
        m = mn; l *= corr;
#pragma unroll
        for (int nd = 0; nd < 4; nd++)
#pragma unroll
          for (int rr = 0; rr < 16; rr++) acc[nd][rr] *= corr;
      }
#pragma unroll
      for (int rr = 0; rr < 16; rr++) {
        sa0[rr] = __builtin_amdgcn_exp2f(sa0[rr] - m);
        sa1[rr] = __builtin_amdgcn_exp2f(sa1[rr] - m);
      }
      {
        float s0 = (sa0[0] + sa0[1]) + (sa0[2] + sa0[3]);
        float s1 = (sa0[4] + sa0[5]) + (sa0[6] + sa0[7]);
        float s2 = (sa0[8] + sa0[9]) + (sa0[10] + sa0[11]);
        float s3 = (sa0[12] + sa0[13]) + (sa0[14] + sa0[15]);
        float s4 = (sa1[0] + sa1[1]) + (sa1[2] + sa1[3]);
        float s5 = (sa1[4] + sa1[5]) + (sa1[6] + sa1[7]);
        float s6 = (sa1[8] + sa1[9]) + (sa1[10] + sa1[11]);
        float s7 = (sa1[12] + sa1[13]) + (sa1[14] + sa1[15]);
        float sum = ((s0 + s1) + (s2 + s3)) + ((s4 + s5) + (s6 + s7));
        sum += __shfl_xor(sum, 32);
        l += sum;
      }

      // ---- P -> bf16 A-frags via v_cvt_pk + shfl_xor(32) (T12) + PV ----
      __builtin_amdgcn_s_setprio(1);
      uint32_t wA = cvtpk(sa0[0], sa0[1]),   wB = cvtpk(sa0[2], sa0[3]);
      uint32_t wC = cvtpk(sa0[4], sa0[5]),   wD = cvtpk(sa0[6], sa0[7]);
      uint32_t wE = cvtpk(sa0[8], sa0[9]),   wF = cvtpk(sa0[10], sa0[11]);
      uint32_t wG = cvtpk(sa0[12], sa0[13]), wH = cvtpk(sa0[14], sa0[15]);
      uint32_t wI = cvtpk(sa1[0], sa1[1]),   wJ = cvtpk(sa1[2], sa1[3]);
      uint32_t wK = cvtpk(sa1[4], sa1[5]),   wL = cvtpk(sa1[6], sa1[7]);
      uint32_t wM = cvtpk(sa1[8], sa1[9]),   wN = cvtpk(sa1[10], sa1[11]);
      uint32_t wO = cvtpk(sa1[12], sa1[13]), wP = cvtpk(sa1[14], sa1[15]);
      uint32_t xA = __shfl_xor(wA, 32), xB = __shfl_xor(wB, 32);
      uint32_t xC = __shfl_xor(wC, 32), xD = __shfl_xor(wD, 32);
      uint32_t xE = __shfl_xor(wE, 32), xF = __shfl_xor(wF, 32);
      uint32_t xG = __shfl_xor(wG, 32), xH = __shfl_xor(wH, 32);
      uint32_t xI = __shfl_xor(wI, 32), xJ = __shfl_xor(wJ, 32);
      uint32_t xK = __shfl_xor(wK, 32), xL = __shfl_xor(wL, 32);
      uint32_t xM = __shfl_xor(wM, 32), xN = __shfl_xor(wN, 32);
      uint32_t xO = __shfl_xor(wO, 32), xP = __shfl_xor(wP, 32);
#pragma unroll
      for (int ks = 0; ks < 4; ks++) {
        u32x4 aw;
        if (ks == 0) {
          aw.x = hi ? xC : wA;  aw.y = hi ? xD : wB;
          aw.z = hi ? wC : xA;  aw.w = hi ? wD : xB;
        } else if (ks == 1) {
          aw.x = hi ? xG : wE;  aw.y = hi ? xH : wF;
          aw.z = hi ? wG : xE;  aw.w = hi ? wH : xF;
        } else if (ks == 2) {
          aw.x = hi ? xK : wI;  aw.y = hi ? xL : wJ;
          aw.z = hi ? wK : xI;  aw.w = hi ? wL : xJ;
        } else {
          aw.x = hi ? xO : wM;  aw.y = hi ? xP : wN;
          aw.z = hi ? wO : xM;  aw.w = hi ? wP : xN;
        }
        bf16x8 af = __builtin_bit_cast(bf16x8, aw);
#pragma unroll
        for (int nd = 0; nd < 4; nd++) {
          bf16x8 vf = *(const bf16x8*)&Vb[cur][(nd * 32 + q31) * 64 + (((2 * ks + hi) ^ kx7) * 8)];
          acc[nd] = __builtin_amdgcn_mfma_f32_32x32x16_bf16(af, vf, acc[nd], 0, 0, 0);
        }
      }
      __builtin_amdgcn_s_setprio(0);
    }
    __syncthreads();
  }

  // ---- epilogue ----
  float linv = 1.f / l;
#pragma unroll
  for (int rr = 0; rr < 16; rr++) {
    int cr = (rr & 3) + 8 * (rr >> 2) + 4 * hi;
    float li = __shfl(linv, cr);
    int sg = rw0 + cr;
    size_t obase = (((size_t)b * 1024 + sg) * 16 + h) * 128 + q31;
#pragma unroll
    for (int nd = 0; nd < 4; nd++)
      aout[obase + nd * 32] = f2bf(acc[nd][rr] * li);
  }
}

// ---------------- launcher ----------------
extern "C" void kernel_launch(void* const* d_in, const int* in_sizes, int n_in,
                              void* d_out, int out_size, void* d_ws, size_t ws_size,
                              hipStream_t stream) {
  const float* hs  = (const float*)d_in[0];
  const float* key = (const float*)d_in[1];
  const float* val = (const float*)d_in[2];
  // d_in[3]: attention_mask — causal, reproduced analytically
  const float* rc  = (const float*)d_in[4];
  const float* rs  = (const float*)d_in[5];
  const float* wq  = (const float*)d_in[6];
  const float* bq  = (const float*)d_in[7];
  const float* wo  = (const float*)d_in[8];
  const float* bo  = (const float*)d_in[9];
  float* out = (float*)d_out;

  char* ws = (char*)d_ws;
  u16* hs_bf = (u16*)(ws);                   // 16 MB ; reused as attn_bf
  u16* wq_bf = (u16*)(ws + 16777216);        //  8 MB
  u16* wo_bf = (u16*)(ws + 25165824);        //  8 MB
  u16* q_bf  = (u16*)(ws + 33554432);        // 16 MB
  u16* kT    = (u16*)(ws + 50331648);        // 16 MB  [bh][s][d]
  u16* vT    = (u16*)(ws + 67108864);        // 16 MB  [bh][d][s]
  u16* attn_bf = hs_bf;                      // hs_bf dead after gemm_rope

  cvt_all<<<16384, 256, 0, stream>>>(hs, wq, wo, hs_bf, wq_bf, wo_bf);

  transpose_cvt<<<dim3(64, 128), 256, 0, stream>>>(key, kT, 128, 1024);   // -> kT[bh][s][d]
  transpose_cvt<<<dim3(64, 128), 256, 0, stream>>>(val, vT, 1024, 128);   // -> vT[bh][d][s]

  gemm256<1><<<dim3(16, 16), 512, 0, stream>>>(hs_bf, wq_bf, bq, rc, rs, q_bf);
  attn_kernel<<<512, 256, 0, stream>>>(q_bf, kT, vT, attn_bf);
  gemm256<0><<<dim3(16, 16), 512, 0, stream>>>(attn_bf, wo_bf, bo, nullptr, nullptr, out);
}

// Round 15
// 149.284 us; speedup vs baseline: 1.1041x; 1.0315x over previous
//
#include <hip/hip_runtime.h>
#include <cstdint>

// CrossLayerAttention on MI355X (gfx950).  B=4 S=1024 H=2048 NH=16 HD=128.
// R15: (1) attn KVBLK 64->32: LDS 32KB/block + sa halved -> 3 blocks/CU
//      (3 barrier domains, 3 waves/SIMD); per-tile math = R9's verified
//      KVBLK=32 form in the R11/R14 4-wave dbuf skeleton; grid map untouched.
//      (2) all prep (cvt x3 + K/V transpose) fused into one kernel launch.
//      gemm256 pipeline unchanged (R11 verified).

typedef unsigned short u16;
typedef __bf16 bf16x8 __attribute__((ext_vector_type(8)));
typedef float  f32x4  __attribute__((ext_vector_type(4)));
typedef float  f32x16 __attribute__((ext_vector_type(16)));
typedef uint32_t u32x4 __attribute__((ext_vector_type(4)));

__device__ __forceinline__ u16 f2bf(float f) {
  uint32_t u = __builtin_bit_cast(uint32_t, f);
  u += 0x7fffu + ((u >> 16) & 1u);   // RNE; inputs finite
  return (u16)(u >> 16);
}
__device__ __forceinline__ uint32_t cvtpk(float lo, float hi) {
  uint32_t r;
  asm("v_cvt_pk_bf16_f32 %0, %1, %2" : "=v"(r) : "v"(lo), "v"(hi));
  return r;
}
__device__ __forceinline__ void gld16(const void* g, void* l) {
  __builtin_amdgcn_global_load_lds(
      (const __attribute__((address_space(1))) void*)g,
      (__attribute__((address_space(3))) void*)l, 16, 0, 0);
}

// ---------------- fused prep: cvt(hs|wq|wo) + transpose_cvt(key) + transpose_cvt(val) ----------------
// blocks [0,16384): cvt; [16384,24576): key 128x1024 -> kT[bh][s][d];
// [24576,32768): val 1024x128 -> vT[bh][d][s].
__global__ __launch_bounds__(256)
void prep_kernel(const float* __restrict__ hs, const float* __restrict__ wq,
                 const float* __restrict__ wo, const float* __restrict__ key,
                 const float* __restrict__ val,
                 u16* __restrict__ hs_o, u16* __restrict__ wq_o,
                 u16* __restrict__ wo_o, u16* __restrict__ kT,
                 u16* __restrict__ vT) {
  __shared__ float tile[32][33];
  const int bx = blockIdx.x, tid = threadIdx.x;
  if (bx < 16384) {
    int i = bx * 256 + tid;                      // [0, 4194304)
    const float* in; u16* out; int j;
    if (i < 2097152)      { in = hs; out = hs_o; j = i; }
    else if (i < 3145728) { in = wq; out = wq_o; j = i - 2097152; }
    else                  { in = wo; out = wo_o; j = i - 3145728; }
    float4 v = ((const float4*)in)[j];
    ushort4 o;
    o.x = f2bf(v.x); o.y = f2bf(v.y); o.z = f2bf(v.z); o.w = f2bf(v.w);
    ((ushort4*)out)[j] = o;
    return;
  }
  const bool isK = bx < 24576;
  const int idx = bx - (isK ? 16384 : 24576);
  const int R = isK ? 128 : 1024, C = isK ? 1024 : 128;
  const int bh = idx >> 7, y = idx & 127;
  const int nct = C >> 5;
  const int rt = y / nct, ct = y % nct;
  const float* src = (isK ? key : val) + (size_t)bh * 131072;
  u16* dst = (isK ? kT : vT) + (size_t)bh * 131072;
  const int r = tid >> 3, c4 = (tid & 7) * 4;
  float4 v = *(const float4*)(src + (size_t)(rt * 32 + r) * C + ct * 32 + c4);
  tile[r][c4 + 0] = v.x; tile[r][c4 + 1] = v.y;
  tile[r][c4 + 2] = v.z; tile[r][c4 + 3] = v.w;
  __syncthreads();
  ushort4 o;
  o.x = f2bf(tile[c4 + 0][r]); o.y = f2bf(tile[c4 + 1][r]);
  o.z = f2bf(tile[c4 + 2][r]); o.w = f2bf(tile[c4 + 3][r]);
  *(ushort4*)(dst + (size_t)(ct * 32 + r) * R + rt * 32 + c4) = o;
}

// ---------------- GEMM: 256x128 tile, BK=64, 3-buf counted-vmcnt pipeline ----------------
// MODE 0: out = A@B^T + bias (fp32 out).  MODE 1: q-proj + fused RoPE (bf16 out,
// scale*log2e folded; head = blockIdx.y; in-wave rope pairing via col interleave).
template<int MODE>
__global__ __launch_bounds__(512, 1)
void gemm256(const u16* __restrict__ A, const u16* __restrict__ Bm,
             const float* __restrict__ bias, const float* __restrict__ cosb,
             const float* __restrict__ sinb, void* __restrict__ Cout) {
  constexpr int K = 2048, N = 2048, NT = 32;
  __shared__ __align__(16) u16 LA[3][256 * 64];   // 3 x 32 KB
  __shared__ __align__(16) u16 LB[3][128 * 64];   // 3 x 16 KB
  const int t = threadIdx.x, lane = t & 63, w = t >> 6;
  const int row0 = blockIdx.x * 256, col0 = blockIdx.y * 128;
  const int wr = (w >> 1) * 64;
  const int g = w & 1;
  const int fr = lane & 15, fg = lane >> 4, fx = fr & 7;
  const int sb8 = ((t & 7) ^ ((t >> 3) & 7)) * 8;
  const u16* gA = A  + (size_t)(row0 + (t >> 3)) * K + sb8;
  const u16* gB = Bm + (size_t)(col0 + (t >> 3)) * K + sb8;
  const int lo8 = t * 8;

  int brow[4];
  if constexpr (MODE == 1) {
    brow[0] = g * 32 + fr;      brow[1] = g * 32 + 16 + fr;
    brow[2] = g * 32 + 64 + fr; brow[3] = g * 32 + 80 + fr;
  } else {
    brow[0] = g * 64 + fr;      brow[1] = g * 64 + 16 + fr;
    brow[2] = g * 64 + 32 + fr; brow[3] = g * 64 + 48 + fr;
  }

  f32x4 acc[4][4] = {};

  auto SA0 = [&](int kt, int buf) {
    const int k0 = kt * 64;
    gld16(gA + k0,                    &LA[buf][lo8]);
    gld16(gA + k0 + (size_t)64 * K,   &LA[buf][4096 + lo8]);
    gld16(gB + k0,                    &LB[buf][lo8]);
  };
  auto SA1 = [&](int kt, int buf) {
    const int k0 = kt * 64;
    gld16(gA + k0 + (size_t)128 * K,  &LA[buf][8192 + lo8]);
    gld16(gA + k0 + (size_t)192 * K,  &LA[buf][12288 + lo8]);
    gld16(gB + k0 + (size_t)64 * K,   &LB[buf][4096 + lo8]);
  };

  SA0(0, 0); SA1(0, 0);
  SA0(1, 1); SA1(1, 1);

  int cb = 0;
  for (int kt = 0; kt < NT; ++kt) {
    const int sbuf = cb >= 1 ? cb - 1 : cb + 2;
    if (kt < NT - 1) asm volatile("s_waitcnt vmcnt(6)" ::: "memory");
    else             asm volatile("s_waitcnt vmcnt(0)" ::: "memory");
    __builtin_amdgcn_s_barrier();
    asm volatile("" ::: "memory");

    bf16x8 af[4][2], bq0[2][2];
#pragma unroll
    for (int mi = 0; mi < 4; mi++)
#pragma unroll
      for (int ks = 0; ks < 2; ks++)
        af[mi][ks] = *(const bf16x8*)&LA[cb][(wr + mi * 16 + fr) * 64 + ((ks * 4 + fg) ^ fx) * 8];
#pragma unroll
    for (int ni = 0; ni < 2; ni++)
#pragma unroll
      for (int ks = 0; ks < 2; ks++)
        bq0[ni][ks] = *(const bf16x8*)&LB[cb][brow[ni] * 64 + ((ks * 4 + fg) ^ fx) * 8];
    if (kt + 2 < NT) SA0(kt + 2, sbuf);
    __builtin_amdgcn_s_setprio(1);
#pragma unroll
    for (int ks = 0; ks < 2; ks++)
#pragma unroll
      for (int mi = 0; mi < 4; mi++)
#pragma unroll
        for (int ni = 0; ni < 2; ni++)
          acc[mi][ni] = __builtin_amdgcn_mfma_f32_16x16x32_bf16(af[mi][ks], bq0[ni][ks], acc[mi][ni], 0, 0, 0);
    __builtin_amdgcn_s_setprio(0);
    __builtin_amdgcn_s_barrier();
    asm volatile("" ::: "memory");

    bf16x8 bq1[2][2];
#pragma unroll
    for (int ni = 0; ni < 2; ni++)
#pragma unroll
      for (int ks = 0; ks < 2; ks++)
        bq1[ni][ks] = *(const bf16x8*)&LB[cb][brow[ni + 2] * 64 + ((ks * 4 + fg) ^ fx) * 8];
    if (kt + 2 < NT) SA1(kt + 2, sbuf);
    __builtin_amdgcn_s_setprio(1);
#pragma unroll
    for (int ks = 0; ks < 2; ks++)
#pragma unroll
      for (int mi = 0; mi < 4; mi++)
#pragma unroll
        for (int ni = 0; ni < 2; ni++)
          acc[mi][ni + 2] = __builtin_amdgcn_mfma_f32_16x16x32_bf16(af[mi][ks], bq1[ni][ks], acc[mi][ni + 2], 0, 0, 0);
    __builtin_amdgcn_s_setprio(0);

    cb = cb == 2 ? 0 : cb + 1;
  }

  if constexpr (MODE == 0) {
#pragma unroll
    for (int mi = 0; mi < 4; mi++)
#pragma unroll
      for (int ni = 0; ni < 4; ni++) {
        int col = col0 + brow[ni];
        float bv = bias[col];
#pragma unroll
        for (int i = 0; i < 4; i++) {
          int row = row0 + wr + mi * 16 + fg * 4 + i;
          ((float*)Cout)[(size_t)row * N + col] = acc[mi][ni][i] + bv;
        }
      }
  } else {
    const int h = blockIdx.y;
    const float SL2E = 0.12751743f;               // (1/sqrt(128)) * log2(e)
    float bv[4];
#pragma unroll
    for (int ni = 0; ni < 4; ni++) bv[ni] = bias[h * 128 + brow[ni]];
    u16* qout = (u16*)Cout;
#pragma unroll
    for (int mi = 0; mi < 4; mi++)
#pragma unroll
      for (int i = 0; i < 4; i++) {
        int row = row0 + wr + mi * 16 + fg * 4 + i;
        int s = row & 1023, bb = row >> 10;
        size_t obase = (((size_t)(bb * 16 + h)) * 1024 + s) * 128;
#pragma unroll
        for (int dp = 0; dp < 2; dp++) {
          int d = g * 32 + dp * 16 + fr;
          float c  = cosb[s * 128 + d] * SL2E;
          float sn = sinb[s * 128 + d] * SL2E;
          float qlo = acc[mi][dp][i] + bv[dp];
          float qhi = acc[mi][dp + 2][i] + bv[dp + 2];
          qout[obase + d]      = f2bf(qlo * c - qhi * sn);
          qout[obase + d + 64] = f2bf(qhi * c + qlo * sn);
        }
      }
  }
}

// ---------------- Flash attention: KVBLK=32, 4 waves, BQ=128, 3 blocks/CU ----------------
// 512 blocks x 256 thr. qt = 7-(x>>6), bh = x&63 (R11 mapping, verified best).
// kv tiles of 32: kt = 0..qt*4+3; wave w computes while kt <= wlast = qt*4+w,
// diag (mask) at kt == wlast. Double-buffered K[32][128]/V^T[128][32] (32KB)
// via gld16 + rule-#21 XOR swizzle. Per-tile math = R9's verified KVBLK=32
// form: swapped QK^T (single sa chain), log2 softmax, cvt_pk pack (2 ks).
__global__ __launch_bounds__(256, 3)
void attn_kernel(const u16* __restrict__ qbf, const u16* __restrict__ kTb,
                 const u16* __restrict__ vTb, u16* __restrict__ aout) {
  __shared__ __align__(16) u16 Kb[2][32 * 128];   // 2 x 8 KB
  __shared__ __align__(16) u16 Vb[2][128 * 32];   // 2 x 8 KB
  const int t = threadIdx.x, lane = t & 63, w = t >> 6;   // w in 0..3
  const int x = blockIdx.x;
  const int qt = 7 - (x >> 6);
  const int bh = x & 63;
  const int b = bh >> 4, h = bh & 15;
  const int q31 = lane & 31, hi = lane >> 5;
  const int kx7 = q31 & 7, kx3 = q31 & 3;
  const u16* kbase = kTb + (size_t)bh * 131072;   // [s][d]
  const u16* vbase = vTb + (size_t)bh * 131072;   // [d][s]

  // staging geometry (pre-swizzled source col, linear LDS dest)
  const int kRow = t >> 4;                        // + p*16 (K: 16 slots/row)
  const int kCb  = (t & 15) ^ (kRow & 7);
  const int vRow = t >> 2;                        // + p*64 (V: 4 slots/row)
  const int vCb  = (t & 3) ^ (vRow & 3);

  const int rw0 = qt * 128 + w * 32;
  const int rowg = rw0 + q31;
  const int last = qt * 4 + 3;
  const int wlast = qt * 4 + w;                   // diag tile for this wave

  bf16x8 qf[8];
#pragma unroll
  for (int ds = 0; ds < 8; ds++)
    qf[ds] = *(const bf16x8*)&qbf[((size_t)bh * 1024 + rowg) * 128 + ds * 16 + hi * 8];

  f32x16 acc[4] = {};
  float m = -3e38f, l = 0.f;

  auto STAGE = [&](int kt, int buf) {
    const u16* ks = kbase + (size_t)(kt * 32 + kRow) * 128 + kCb * 8;
    const u16* vs = vbase + (size_t)vRow * 1024 + kt * 32 + vCb * 8;
    u16* kl = &Kb[buf][t * 8];
    u16* vl = &Vb[buf][t * 8];
#pragma unroll
    for (int p = 0; p < 2; p++) {
      gld16(ks + (size_t)p * 16 * 128, kl + p * 2048);
      gld16(vs + (size_t)p * 64 * 1024, vl + p * 2048);
    }
  };

  STAGE(0, 0);
  __syncthreads();
  for (int kt = 0; kt <= last; kt++) {
    const int cur = kt & 1;
    if (kt < last) STAGE(kt + 1, cur ^ 1);
    if (kt <= wlast) {
      // ---- QK^T (swapped): sa = S^T[kv 0..31][q], log2 domain ----
      f32x16 sa = {};
      __builtin_amdgcn_s_setprio(1);
#pragma unroll
      for (int ds = 0; ds < 8; ds++) {
        bf16x8 kf = *(const bf16x8*)&Kb[cur][q31 * 128 + (((2 * ds + hi) ^ kx7) * 8)];
        sa = __builtin_amdgcn_mfma_f32_32x32x16_bf16(kf, qf[ds], sa, 0, 0, 0);
      }
      __builtin_amdgcn_s_setprio(0);

      // ---- mask (diag tile only) ----
      if (kt == wlast) {
#pragma unroll
        for (int rr = 0; rr < 16; rr++) {
          int cr = (rr & 3) + 8 * (rr >> 2) + 4 * hi;
          if (kt * 32 + cr > rowg) sa[rr] = -1e9f;
        }
      }
      // ---- row max: max3-fusable tree + cross-half ----
      float t0 = fmaxf(fmaxf(sa[0], sa[1]), sa[2]);
      float t1 = fmaxf(fmaxf(sa[3], sa[4]), sa[5]);
      float t2 = fmaxf(fmaxf(sa[6], sa[7]), sa[8]);
      float t3 = fmaxf(fmaxf(sa[9], sa[10]), sa[11]);
      float t4 = fmaxf(fmaxf(sa[12], sa[13]), sa[14]);
      float mx = fmaxf(fmaxf(fmaxf(t0, t1), t2),
                       fmaxf(fmaxf(t3, t4), sa[15]));
      mx = fmaxf(mx, __shfl_xor(mx, 32));
      if (!__all(mx - m <= 11.5f)) {              // defer-max (T13, log2 units)
        float mn = fmaxf(m, mx);
        float corr = __builtin_amdgcn_exp2f(m - mn);
        m = mn; l *= corr;
#pragma unroll
        for (int nd = 0; nd < 4; nd++)
#pragma unroll
          for (int rr = 0; rr < 16; rr++) acc[nd][rr] *= corr;
      }
#pragma unroll
      for (int rr = 0; rr < 16; rr++) sa[rr] = __builtin_amdgcn_exp2f(sa[rr] - m);
      {
        float s0 = (sa[0] + sa[1]) + (sa[2] + sa[3]);
        float s1 = (sa[4] + sa[5]) + (sa[6] + sa[7]);
        float s2 = (sa[8] + sa[9]) + (sa[10] + sa[11]);
        float s3 = (sa[12] + sa[13]) + (sa[14] + sa[15]);
        float sum = (s0 + s1) + (s2 + s3);
        sum += __shfl_xor(sum, 32);
        l += sum;
      }

      // ---- P -> bf16 A-frags via v_cvt_pk + shfl_xor(32) (T12, R9 form) + PV ----
      __builtin_amdgcn_s_setprio(1);
      uint32_t wA = cvtpk(sa[0], sa[1]),   wB = cvtpk(sa[2], sa[3]);
      uint32_t wC = cvtpk(sa[4], sa[5]),   wD = cvtpk(sa[6], sa[7]);
      uint32_t wE = cvtpk(sa[8], sa[9]),   wF = cvtpk(sa[10], sa[11]);
      uint32_t wG = cvtpk(sa[12], sa[13]), wH = cvtpk(sa[14], sa[15]);
      uint32_t xA = __shfl_xor(wA, 32), xB = __shfl_xor(wB, 32);
      uint32_t xC = __shfl_xor(wC, 32), xD = __shfl_xor(wD, 32);
      uint32_t xE = __shfl_xor(wE, 32), xF = __shfl_xor(wF, 32);
      uint32_t xG = __shfl_xor(wG, 32), xH = __shfl_xor(wH, 32);
#pragma unroll
      for (int ks = 0; ks < 2; ks++) {
        u32x4 aw;
        if (ks == 0) {
          aw.x = hi ? xC : wA;  aw.y = hi ? xD : wB;
          aw.z = hi ? wC : xA;  aw.w = hi ? wD : xB;
        } else {
          aw.x = hi ? xG : wE;  aw.y = hi ? xH : wF;
          aw.z = hi ? wG : xE;  aw.w = hi ? wH : xF;
        }
        bf16x8 af = __builtin_bit_cast(bf16x8, aw);
#pragma unroll
        for (int nd = 0; nd < 4; nd++) {
          bf16x8 vf = *(const bf16x8*)&Vb[cur][(nd * 32 + q31) * 32 + (((2 * ks + hi) ^ kx3) * 8)];
          acc[nd] = __builtin_amdgcn_mfma_f32_32x32x16_bf16(af, vf, acc[nd], 0, 0, 0);
        }
      }
      __builtin_amdgcn_s_setprio(0);
    }
    __syncthreads();
  }

  // ---- epilogue: O[q][d], rows cr(rr,hi), cols nd*32+q31 ----
  float linv = 1.f / l;
#pragma unroll
  for (int rr = 0; rr < 16; rr++) {
    int cr = (rr & 3) + 8 * (rr >> 2) + 4 * hi;
    float li = __shfl(linv, cr);
    int sg = rw0 + cr;
    size_t obase = (((size_t)b * 1024 + sg) * 16 + h) * 128 + q31;
#pragma unroll
    for (int nd = 0; nd < 4; nd++)
      aout[obase + nd * 32] = f2bf(acc[nd][rr] * li);
  }
}

// ---------------- launcher ----------------
extern "C" void kernel_launch(void* const* d_in, const int* in_sizes, int n_in,
                              void* d_out, int out_size, void* d_ws, size_t ws_size,
                              hipStream_t stream) {
  const float* hs  = (const float*)d_in[0];
  const float* key = (const float*)d_in[1];
  const float* val = (const float*)d_in[2];
  // d_in[3]: attention_mask — causal, reproduced analytically
  const float* rc  = (const float*)d_in[4];
  const float* rs  = (const float*)d_in[5];
  const float* wq  = (const float*)d_in[6];
  const float* bq  = (const float*)d_in[7];
  const float* wo  = (const float*)d_in[8];
  const float* bo  = (const float*)d_in[9];
  float* out = (float*)d_out;

  char* ws = (char*)d_ws;
  u16* hs_bf = (u16*)(ws);                   // 16 MB ; reused as attn_bf
  u16* wq_bf = (u16*)(ws + 16777216);        //  8 MB
  u16* wo_bf = (u16*)(ws + 25165824);        //  8 MB
  u16* q_bf  = (u16*)(ws + 33554432);        // 16 MB
  u16* kT    = (u16*)(ws + 50331648);        // 16 MB  [bh][s][d]
  u16* vT    = (u16*)(ws + 67108864);        // 16 MB  [bh][d][s]
  u16* attn_bf = hs_bf;                      // hs_bf dead after gemm_rope

  prep_kernel<<<32768, 256, 0, stream>>>(hs, wq, wo, key, val,
                                         hs_bf, wq_bf, wo_bf, kT, vT);

  gemm256<1><<<dim3(16, 16), 512, 0, stream>>>(hs_bf, wq_bf, bq, rc, rs, q_bf);
  attn_kernel<<<512, 256, 0, stream>>>(q_bf, kT, vT, attn_bf);
  gemm256<0><<<dim3(16, 16), 512, 0, stream>>>(attn_bf, wo_bf, bo, nullptr, nullptr, out);
}